// Round 2
// baseline (371.452 us; speedup 1.0000x reference)
//
#include <hip/hip_runtime.h>

// Problem constants (from reference setup_inputs)
#define RES        64
#define NFRAMES    16
#define PPT        4     // points per thread (independent gathers in flight)

// inputs (d_in order): pts(N,3) f32, bidx(N) i32, ts(N) f32,
//                      occ_grid(256,64,64,64) f32, ts_keyframes(16) f32, num_frames(1) i32
// output: (N,) f32

__global__ __launch_bounds__(256) void occ_gather_kernel(
    const float* __restrict__ pts,
    const int*   __restrict__ bidx,
    const float* __restrict__ ts,
    const float* __restrict__ occ,
    const float* __restrict__ keys,
    float*       __restrict__ out,
    int n)
{
    __shared__ float skeys[NFRAMES];
    if (threadIdx.x < NFRAMES) skeys[threadIdx.x] = keys[threadIdx.x];
    __syncthreads();

    const int tid    = blockIdx.x * blockDim.x + threadIdx.x;
    const int stride = gridDim.x * blockDim.x;

    int   idxv[PPT];
    float pxv[PPT], pyv[PPT], pzv[PPT], tv[PPT];
    int   bv[PPT];
    bool  ok[PPT];

    // 1) issue all streaming loads (independent, coalesced per wave)
    #pragma unroll
    for (int k = 0; k < PPT; ++k) {
        int idx = tid + k * stride;
        idxv[k] = idx;
        ok[k] = idx < n;
        if (ok[k]) {
            pxv[k] = pts[idx * 3 + 0];
            pyv[k] = pts[idx * 3 + 1];
            pzv[k] = pts[idx * 3 + 2];
            tv[k]  = ts[idx];
            bv[k]  = bidx[idx];
        }
    }

    // 2) compute flat offsets, then issue all gathers independently
    unsigned int off[PPT];
    #pragma unroll
    for (int k = 0; k < PPT; ++k) {
        if (!ok[k]) continue;
        int gx = min(max((int)floorf((pxv[k] * 0.5f + 0.5f) * (float)RES), 0), RES - 1);
        int gy = min(max((int)floorf((pyv[k] * 0.5f + 0.5f) * (float)RES), 0), RES - 1);
        int gz = min(max((int)floorf((pzv[k] * 0.5f + 0.5f) * (float)RES), 0), RES - 1);

        // searchsorted(side='left') == count of keys strictly < t
        int i = 0;
        #pragma unroll
        for (int j = 0; j < NFRAMES; ++j) i += (skeys[j] < tv[k]) ? 1 : 0;
        i = min(max(i, 1), NFRAMES - 1);
        float l = skeys[i - 1];
        float r = skeys[i];
        int f = (tv[k] - l <= r - tv[k]) ? (i - 1) : i;

        off[k] = ((unsigned int)(bv[k] * NFRAMES + f) << 18)
               | ((unsigned int)gx << 12)
               | ((unsigned int)gy << 6)
               |  (unsigned int)gz;
    }

    // 3) gathers (4 independent loads in flight per thread) + stores
    float val[PPT];
    #pragma unroll
    for (int k = 0; k < PPT; ++k) {
        if (ok[k]) val[k] = occ[off[k]];
    }
    #pragma unroll
    for (int k = 0; k < PPT; ++k) {
        if (ok[k]) out[idxv[k]] = val[k];
    }
}

extern "C" void kernel_launch(void* const* d_in, const int* in_sizes, int n_in,
                              void* d_out, int out_size, void* d_ws, size_t ws_size,
                              hipStream_t stream) {
    const float* pts  = (const float*)d_in[0];
    const int*   bidx = (const int*)  d_in[1];
    const float* ts   = (const float*)d_in[2];
    const float* occ  = (const float*)d_in[3];
    const float* keys = (const float*)d_in[4];
    float* out = (float*)d_out;

    int n = in_sizes[2];  // NUM_PTS (ts element count)
    int blocks = (n + 256 * PPT - 1) / (256 * PPT);
    occ_gather_kernel<<<blocks, 256, 0, stream>>>(pts, bidx, ts, occ, keys, out, n);
}